// Round 1
// baseline (433.545 us; speedup 1.0000x reference)
//
#include <hip/hip_runtime.h>
#include <math.h>

// Fastfood layer: out[row, m*1024+i] =
//   cos( (1/32) * S[m]*FWHT(G[m]*FWHT(B[m]*x[row])[P[m]]) + 2*pi*u ) * (1/64)
//
// One wave (64 lanes) per row; 16 elements/lane, logical index i = lane*16 + k.
// FWHT-1024 = 4 in-register stages (bits 0-3 in k) + 6 cross-lane shfl_xor
// stages (bits 4-9 in lane). Permutation gather via per-wave LDS region
// (intra-wave DS ops are processed in order; no barrier needed).

__device__ __forceinline__ void fwht1024_wave(float v[16], int lane) {
    // In-register stages: logical h = 1,2,4,8  (bits 0-3 = register index k)
#pragma unroll
    for (int h = 1; h < 16; h <<= 1) {
#pragma unroll
        for (int k = 0; k < 16; ++k) {
            if (!(k & h)) {
                float a = v[k], b = v[k ^ h];
                v[k] = a + b;
                v[k ^ h] = a - b;
            }
        }
    }
    // Cross-lane stages: logical h = 16..512  (bits 4-9 = lane bits 0-5)
#pragma unroll
    for (int h = 1; h <= 32; h <<= 1) {
#pragma unroll
        for (int k = 0; k < 16; ++k) {
            float t = __shfl_xor(v[k], h, 64);
            v[k] = (lane & h) ? (t - v[k]) : (v[k] + t);
        }
    }
}

__global__ __launch_bounds__(256) void fastfood_kernel(
    const float* __restrict__ x, const float* __restrict__ B,
    const float* __restrict__ G, const float* __restrict__ S,
    const int* __restrict__ P, const float* __restrict__ u_rand,
    float* __restrict__ out)
{
    __shared__ float lds[4][1024];   // one 4KB scratch region per wave
    const int lane = threadIdx.x & 63;
    const int wv   = threadIdx.x >> 6;
    const int row  = (blockIdx.x << 2) + wv;
    if (row >= 8192) return;

    // Load x row once: i = lane*16 + k, contiguous 16 floats per lane
    float xv[16];
    {
        const float4* x4 = (const float4*)(x + (size_t)row * 1024);
#pragma unroll
        for (int j = 0; j < 4; ++j) {
            float4 t = x4[lane * 4 + j];
            xv[4 * j + 0] = t.x; xv[4 * j + 1] = t.y;
            xv[4 * j + 2] = t.z; xv[4 * j + 3] = t.w;
        }
    }

    float* wlds = lds[wv];
    const float c_arg = 0.03125f * 0.15915494309189535f; // (1/32) * (1/2pi)
    const float c_amp = 0.015625f;                        // sqrt(2/8192) = 1/64

    for (int m = 0; m < 8; ++m) {
        float v[16];
        // v = x * B[m]
        {
            const float4* B4 = (const float4*)(B + m * 1024);
#pragma unroll
            for (int j = 0; j < 4; ++j) {
                float4 b = B4[lane * 4 + j];
                v[4 * j + 0] = xv[4 * j + 0] * b.x;
                v[4 * j + 1] = xv[4 * j + 1] * b.y;
                v[4 * j + 2] = xv[4 * j + 2] * b.z;
                v[4 * j + 3] = xv[4 * j + 3] * b.w;
            }
        }

        fwht1024_wave(v, lane);

        // Stage HBx into per-wave LDS (contiguous b128 writes)
        {
            float4* w4 = (float4*)wlds;
#pragma unroll
            for (int j = 0; j < 4; ++j)
                w4[lane * 4 + j] =
                    make_float4(v[4 * j + 0], v[4 * j + 1], v[4 * j + 2], v[4 * j + 3]);
        }

        // Gather with P[m], multiply by G[m]
        {
            const int4*   P4 = (const int4*)(P + m * 1024);
            const float4* G4 = (const float4*)(G + m * 1024);
#pragma unroll
            for (int j = 0; j < 4; ++j) {
                int4 p   = P4[lane * 4 + j];
                float4 g = G4[lane * 4 + j];
                v[4 * j + 0] = wlds[p.x] * g.x;
                v[4 * j + 1] = wlds[p.y] * g.y;
                v[4 * j + 2] = wlds[p.z] * g.z;
                v[4 * j + 3] = wlds[p.w] * g.w;
            }
        }

        fwht1024_wave(v, lane);

        // Epilogue: *S, *(1/32), cos(val + 2*pi*u) * (1/64), store
        {
            const float4* S4 = (const float4*)(S + m * 1024);
            const float4* U4 = (const float4*)(u_rand + m * 1024);
            float4* o4 = (float4*)(out + (size_t)row * 8192 + m * 1024);
#pragma unroll
            for (int j = 0; j < 4; ++j) {
                float4 s = S4[lane * 4 + j];
                float4 u = U4[lane * 4 + j];
                float4 r;
                // cos(2*pi*t), t in revolutions; fract for range reduction
                r.x = __builtin_amdgcn_cosf(__builtin_amdgcn_fractf(
                          fmaf(v[4 * j + 0] * s.x, c_arg, u.x))) * c_amp;
                r.y = __builtin_amdgcn_cosf(__builtin_amdgcn_fractf(
                          fmaf(v[4 * j + 1] * s.y, c_arg, u.y))) * c_amp;
                r.z = __builtin_amdgcn_cosf(__builtin_amdgcn_fractf(
                          fmaf(v[4 * j + 2] * s.z, c_arg, u.z))) * c_amp;
                r.w = __builtin_amdgcn_cosf(__builtin_amdgcn_fractf(
                          fmaf(v[4 * j + 3] * s.w, c_arg, u.w))) * c_amp;
                o4[lane * 4 + j] = r;
            }
        }
    }
}

extern "C" void kernel_launch(void* const* d_in, const int* in_sizes, int n_in,
                              void* d_out, int out_size, void* d_ws, size_t ws_size,
                              hipStream_t stream) {
    const float* x  = (const float*)d_in[0];
    const float* B  = (const float*)d_in[1];
    const float* G  = (const float*)d_in[2];
    const float* S  = (const float*)d_in[3];
    const int*   P  = (const int*)d_in[4];
    const float* u  = (const float*)d_in[5];
    float* out = (float*)d_out;

    dim3 grid(2048), block(256);
    hipLaunchKernelGGL(fastfood_kernel, grid, block, 0, stream,
                       x, B, G, S, P, u, out);
}